// Round 12
// baseline (2302.269 us; speedup 1.0000x reference)
//
#include <hip/hip_runtime.h>
#include <hip/hip_cooperative_groups.h>
#include <cstdint>
#include <cstddef>

namespace cg = cooperative_groups;

#define BB 8
#define SS 2
#define TT 512
#define CC 2048
#define ND 1024
#define AD 16384
#define NN 256
#define AN 2048
#define NEGV -1e30f
#define NTH 1024   // fwd block threads == number of arc chunks per graph
#define NWG 256    // grid: 16 den + 32 num + 208 wprep workers

// ---------------------------------------------------------------------------
// prep: counting sort of arcs by dst (CSR order) into chunk-transposed SoA
//   meta = gidx | dst<<16   (gidx = LDS gather index into dual-copy alpha)
//   pxi[p] = pdf, wcsr[p] = weight (CSR order, for the W' precompute)
// plus partial-slot tables for the segmented merge. Two-choice bank-balanced
// dual-copy gather indices baked into meta (value read identical either way).
// ---------------------------------------------------------------------------
__global__ void prep_kernel(const int* __restrict__ src, const int* __restrict__ dst,
                            const int* __restrict__ pdf, const float* __restrict__ w,
                            unsigned* __restrict__ meta_t, unsigned* __restrict__ pxi,
                            float* __restrict__ wcsr,
                            int* __restrict__ pbeg, int* __restrict__ padj,
                            int N, int A, int LC)
{
    __shared__ int cnt[1024];
    __shared__ int pos[1024];
    __shared__ unsigned char gcnt[8192];
    const int g = blockIdx.x;
    src += (size_t)g * A; dst += (size_t)g * A; pdf += (size_t)g * A; w += (size_t)g * A;
    meta_t += (size_t)g * A; pxi += (size_t)g * A; wcsr += (size_t)g * A;
    pbeg += (size_t)g * (N + 1); padj += (size_t)g * N;
    const int tid = threadIdx.x;
    cnt[tid] = 0;
    __syncthreads();
    for (int a = tid; a < A; a += blockDim.x) atomicAdd(&cnt[dst[a]], 1);
    __syncthreads();
    const int deg = cnt[tid];
    pos[tid] = deg;
    __syncthreads();
    for (int off = 1; off < blockDim.x; off <<= 1) {
        int add = (tid >= off) ? pos[tid - off] : 0;
        __syncthreads();
        pos[tid] += add;
        __syncthreads();
    }
    const int r0 = pos[tid] - deg;
    const int np = deg ? (((r0 + deg - 1) >> LC) - (r0 >> LC) + 1) : 0;
    __syncthreads();
    pos[tid] = np;
    __syncthreads();
    for (int off = 1; off < blockDim.x; off <<= 1) {
        int add = (tid >= off) ? pos[tid - off] : 0;
        __syncthreads();
        pos[tid] += add;
        __syncthreads();
    }
    const int pexcl = pos[tid] - np;
    pbeg[tid] = pexcl;
    if (tid == blockDim.x - 1) pbeg[N] = pexcl + np;
    padj[tid] = pexcl - (r0 >> LC);
    cnt[tid] = r0;
    __syncthreads();
    for (int a = tid; a < A; a += blockDim.x) {
        const int d2 = dst[a];
        const int p = atomicAdd(&cnt[d2], 1);
        const int l = p >> LC;
        const int i = p & ((1 << LC) - 1);
        meta_t[(size_t)i * NTH + l] = (unsigned)src[a] | ((unsigned)d2 << 16);
        pxi[p] = (unsigned)pdf[a];
        wcsr[p] = w[a];
    }
    __syncthreads();
    const int CH = 1 << LC;
    const int ngrp = (NTH / 64) * CH;
    if (tid < ngrp) {
        unsigned char* cb = &gcnt[tid * 32];
        for (int b = 0; b < 32; ++b) cb[b] = 0;
        const int i = tid & (CH - 1);
        const int w2 = tid >> LC;
        for (int lane = 0; lane < 64; ++lane) {
            const size_t idx = (size_t)i * NTH + (w2 * 64 + lane);
            const unsigned mt = meta_t[idx];
            const unsigned sv = mt & 0xffffu;
            const unsigned alt = sv ^ ((sv >> 5) & 31u);
            const int b0 = (int)(sv & 31u), b1 = (int)(alt & 31u);
            unsigned gx;
            if (cb[b1] < cb[b0]) { cb[b1]++; gx = (unsigned)N + alt; }
            else                 { cb[b0]++; gx = sv; }
            meta_t[idx] = (mt & 0xffff0000u) | gx;
        }
    }
}

// ---------------------------------------------------------------------------
// W' production for one time tile: W'[inst][trel][pos] = llh[t][pdf] + w
// (weight folded in — verified r8-r11). Row staged in LDS; float4 I/O.
// ---------------------------------------------------------------------------
__device__ void wprep_part(int ub, int nb, int t0, int Tt, const float* __restrict__ est,
                           const unsigned* __restrict__ pxi_den,
                           const float* __restrict__ wcsr_den,
                           const unsigned* __restrict__ pxi_num,
                           const float* __restrict__ wcsr_num,
                           float* __restrict__ Wd, float* __restrict__ Wn,
                           float* row_s)
{
    const int tid = threadIdx.x;
    const int nden = 16 * Tt;
    const int total = nden + 32 * Tt;
    for (int u = ub; u < total; u += nb) {
        __syncthreads();   // previous unit's row_s readers done
        const float* row; const unsigned* pxi; const float* wcs; float* out; int n4;
        if (u < nden) {
            const int inst = u / Tt, trel = u - inst * Tt;
            const int s = inst >> 3, b = inst & 7;
            row = est + ((size_t)(b * SS + s) * TT + (t0 + trel)) * CC;
            pxi = pxi_den; wcs = wcsr_den;
            out = Wd + ((size_t)inst * Tt + trel) * AD;
            n4 = AD >> 2;
        } else {
            const int v = u - nden;
            const int inst = v / Tt, trel = v - inst * Tt;   // inst = p*16+g
            const int gg = inst & 15, p = inst >> 4;
            const int s = gg >> 3, b = gg & 7;
            const int sp = p ? (1 - s) : s;
            row = est + ((size_t)(b * SS + sp) * TT + (t0 + trel)) * CC;
            pxi = pxi_num + (size_t)gg * AN; wcs = wcsr_num + (size_t)gg * AN;
            out = Wn + ((size_t)inst * Tt + trel) * AN;
            n4 = AN >> 2;
        }
        row_s[tid] = row[tid]; row_s[tid + 1024] = row[tid + 1024];
        __syncthreads();
        const uint4* p4 = (const uint4*)pxi;
        const float4* w4 = (const float4*)wcs;
        float4* o4 = (float4*)out;
        for (int k = tid; k < n4; k += 1024) {
            const uint4 pp = p4[k];
            const float4 ww = w4[k];
            o4[k] = make_float4(row_s[pp.x] + ww.x, row_s[pp.y] + ww.y,
                                row_s[pp.z] + ww.z, row_s[pp.w] + ww.w);
        }
    }
}

__global__ __launch_bounds__(1024) void wprep0_kernel(
    const float* __restrict__ est,
    const unsigned* __restrict__ pxi_den, const float* __restrict__ wcsr_den,
    const unsigned* __restrict__ pxi_num, const float* __restrict__ wcsr_num,
    float* __restrict__ Wd, float* __restrict__ Wn, int t0, int Tt)
{
    __shared__ float row_s[CC];
    wprep_part(blockIdx.x, gridDim.x, t0, Tt, est, pxi_den, wcsr_den,
               pxi_num, wcsr_num, Wd, Wn, row_s);
}

template<int CH>
__device__ inline void load_w_row(const float* __restrict__ p, float* dst)
{
    if constexpr (CH == 16) {
        const float4* p4 = (const float4*)p;
        const float4 a = p4[0], b = p4[1], c = p4[2], d = p4[3];
        dst[0]=a.x;  dst[1]=a.y;  dst[2]=a.z;  dst[3]=a.w;
        dst[4]=b.x;  dst[5]=b.y;  dst[6]=b.z;  dst[7]=b.w;
        dst[8]=c.x;  dst[9]=c.y;  dst[10]=c.z; dst[11]=c.w;
        dst[12]=d.x; dst[13]=d.y; dst[14]=d.z; dst[15]=d.w;
    } else {
        const float2 v = *(const float2*)p;
        dst[0] = v.x; dst[1] = v.y;
    }
}

// ---------------------------------------------------------------------------
// One FSM time step (r10-verified math, verbatim):
//   phase 1: batch dual-copy gathers; two-pass segmented LSE; (m,sum)
//            partials to consecutive pk slots
//   phase 2: owner merges <=4 partials; writes both alpha copies
//   reference semantics: mc=max(m,NEG); s'=s*exp(m-mc); new=mc+log(max(s',1e-30))
// ---------------------------------------------------------------------------
template<int CH>
__device__ inline void fsm_step(const unsigned* meta, unsigned segmask, int slot0,
                                bool st, int pb0, int pb1, int N,
                                const float* wc, float* alpha_s, float2* pk)
{
    const int tid = threadIdx.x;
    float av[CH];
#pragma unroll
    for (int i = 0; i < CH; ++i)
        av[i] = alpha_s[meta[i] & 0xffffu];
    float sc[CH];
#pragma unroll
    for (int i = 0; i < CH; ++i)
        sc[i] = av[i] + wc[i];          // wc = weight + llh (folded)
    float pm[CH];
    {
        float m = -INFINITY;
#pragma unroll
        for (int i = 0; i < CH; ++i) {
            m = fmaxf(m, sc[i]);
            pm[i] = m;
            if (segmask & (1u << i)) m = -INFINITY;
        }
    }
    float sm[CH];
    sm[CH - 1] = pm[CH - 1];
#pragma unroll
    for (int i = CH - 2; i >= 0; --i)
        sm[i] = (segmask & (1u << i)) ? pm[i] : sm[i + 1];
    {
        float ssn = 0.f;
        int sl = slot0;
#pragma unroll
        for (int i = 0; i < CH; ++i) {
            ssn += __expf(sc[i] - sm[i]);
            if (segmask & (1u << i)) {
                pk[sl] = make_float2(sm[i], ssn); ++sl;
                ssn = 0.f;
            }
        }
    }
    __syncthreads();                                 // partials + alpha reads done
    if (st) {
        float v2;
        const int cnt = pb1 - pb0;
        if (cnt > 0) {
            const float2 P0 = pk[pb0];
            const float2 P1 = pk[cnt > 1 ? pb0 + 1 : pb0];
            const float2 P2 = pk[cnt > 2 ? pb0 + 2 : pb0];
            const float2 P3 = pk[cnt > 3 ? pb0 + 3 : pb0];
            float mm = P0.x, s2 = P0.y;
            if (cnt > 1) {
                const float d = P1.x - mm; const float e = __expf(-fabsf(d));
                if (d > 0.f) { s2 = s2 * e + P1.y; mm = P1.x; } else { s2 += P1.y * e; }
            }
            if (cnt > 2) {
                const float d = P2.x - mm; const float e = __expf(-fabsf(d));
                if (d > 0.f) { s2 = s2 * e + P2.y; mm = P2.x; } else { s2 += P2.y * e; }
            }
            if (cnt > 3) {
                const float d = P3.x - mm; const float e = __expf(-fabsf(d));
                if (d > 0.f) { s2 = s2 * e + P3.y; mm = P3.x; } else { s2 += P3.y * e; }
            }
            for (int q2 = pb0 + 4; q2 < pb1; ++q2) {  // rare
                const float2 Pq = pk[q2];
                const float d = Pq.x - mm; const float e = __expf(-fabsf(d));
                if (d > 0.f) { s2 = s2 * e + Pq.y; mm = Pq.x; } else { s2 += Pq.y * e; }
            }
            const float mc  = fmaxf(mm, NEGV);
            const float scs = s2 * __expf(mm - mc);
            v2 = mc + __logf(fmaxf(scs, 1e-30f));
        } else {
            v2 = NEGV + __logf(1e-30f);              // no in-arcs (matches ref)
        }
        alpha_s[tid] = v2;
        alpha_s[N + (tid ^ ((tid >> 5) & 31))] = v2;
    }
    __syncthreads();
}

// ---------------------------------------------------------------------------
// launch-per-tile path (r10-verified fallback): forward over one tile with
// alpha persisted in global between launches.
// ---------------------------------------------------------------------------
template<int CH>
__device__ void fsm_forward_tile(int N, int L, int t0, int Tt, bool first, bool last,
    const float* __restrict__ Wrow0, int wstride,
    const unsigned* __restrict__ meta_g,
    const int* __restrict__ pbeg_g, const int* __restrict__ padj_g,
    const float* __restrict__ initv, const float* __restrict__ finalv,
    float* __restrict__ alpha_gl, float* __restrict__ res,
    float* alpha_s, float2* pk)
{
    const int tid = threadIdx.x;
    unsigned meta[CH];
#pragma unroll
    for (int i = 0; i < CH; ++i) meta[i] = meta_g[i * NTH + tid];
    unsigned segmask = 0;
#pragma unroll
    for (int i = 0; i < CH; ++i) {
        const int di = (int)(meta[i] >> 16);
        const int dn = (i + 1 < CH) ? (int)(meta[i + 1] >> 16) : -1;
        if (di != dn) segmask |= (1u << i);
    }
    const int slot0 = padj_g[meta[0] >> 16] + tid;
    const bool st = tid < N;
    int pb0 = 0, pb1 = 0; float fin = 0.f;
    if (st) {
        const float a0 = first ? initv[tid] : alpha_gl[tid];
        alpha_s[tid] = a0;
        alpha_s[N + (tid ^ ((tid >> 5) & 31))] = a0;
        pb0 = pbeg_g[tid]; pb1 = pbeg_g[tid + 1];
        fin = finalv[tid];
    }
    int tb = L - t0; if (tb > Tt) tb = Tt; if (tb < 0) tb = 0;
    float wc[CH];
    if (tb > 0) load_w_row<CH>(Wrow0 + (size_t)tid * CH, wc);
    __syncthreads();

    for (int trel = 0; trel < tb; ++trel) {
        const bool pre = (trel + 1 < tb);
        float wn[CH];
        if (pre)
            load_w_row<CH>(Wrow0 + (size_t)(trel + 1) * wstride + (size_t)tid * CH, wn);
        fsm_step<CH>(meta, segmask, slot0, st, pb0, pb1, N, wc, alpha_s, pk);
        if (pre) {
#pragma unroll
            for (int i = 0; i < CH; ++i) wc[i] = wn[i];
        }
    }

    if (last) {
        const float v = st ? (alpha_s[tid] + fin) : -INFINITY;
        float* red = (float*)pk;
        red[tid] = v;
        __syncthreads();
        for (int off = 512; off > 0; off >>= 1) {
            if (tid < off) red[tid] = fmaxf(red[tid], red[tid + off]);
            __syncthreads();
        }
        const float M = red[0];
        __syncthreads();
        red[tid] = __expf(v - M);
        __syncthreads();
        for (int off = 512; off > 0; off >>= 1) {
            if (tid < off) red[tid] += red[tid + off];
            __syncthreads();
        }
        if (tid == 0) *res = M + __logf(red[0]);
    } else if (st) {
        alpha_gl[tid] = alpha_s[tid];
    }
}

// ---------------------------------------------------------------------------
// persistent path: all nt tiles in one cooperative kernel; alpha and meta
// stay resident; grid.sync() at tile boundaries swaps the W' double buffer.
// ---------------------------------------------------------------------------
template<int CH>
__device__ void fsm_forward_persist(cg::grid_group grid,
    int N, int L, int nt, int Tt,
    const float* __restrict__ W0, const float* __restrict__ W1, int wstride,
    const unsigned* __restrict__ meta_g,
    const int* __restrict__ pbeg_g, const int* __restrict__ padj_g,
    const float* __restrict__ initv, const float* __restrict__ finalv,
    float* __restrict__ res, float* alpha_s, float2* pk)
{
    const int tid = threadIdx.x;
    unsigned meta[CH];
#pragma unroll
    for (int i = 0; i < CH; ++i) meta[i] = meta_g[i * NTH + tid];
    unsigned segmask = 0;
#pragma unroll
    for (int i = 0; i < CH; ++i) {
        const int di = (int)(meta[i] >> 16);
        const int dn = (i + 1 < CH) ? (int)(meta[i + 1] >> 16) : -1;
        if (di != dn) segmask |= (1u << i);
    }
    const int slot0 = padj_g[meta[0] >> 16] + tid;
    const bool st = tid < N;
    int pb0 = 0, pb1 = 0; float fin = 0.f;
    if (st) {
        const float a0 = initv[tid];
        alpha_s[tid] = a0;
        alpha_s[N + (tid ^ ((tid >> 5) & 31))] = a0;
        pb0 = pbeg_g[tid]; pb1 = pbeg_g[tid + 1];
        fin = finalv[tid];
    }
    __syncthreads();

    for (int k = 0; k < nt; ++k) {
        const float* __restrict__ Wrow0 = (k & 1) ? W1 : W0;
        const int t0 = k * Tt;
        int tb = L - t0; if (tb > Tt) tb = Tt; if (tb < 0) tb = 0;
        float wc[CH];
        if (tb > 0) load_w_row<CH>(Wrow0 + (size_t)tid * CH, wc);
        for (int trel = 0; trel < tb; ++trel) {
            const bool pre = (trel + 1 < tb);
            float wn[CH];
            if (pre)
                load_w_row<CH>(Wrow0 + (size_t)(trel + 1) * wstride + (size_t)tid * CH, wn);
            fsm_step<CH>(meta, segmask, slot0, st, pb0, pb1, N, wc, alpha_s, pk);
            if (pre) {
#pragma unroll
                for (int i = 0; i < CH; ++i) wc[i] = wn[i];
            }
        }
        if (k + 1 < nt) grid.sync();   // next tile's W' ready; buffer swap
    }

    // final logsumexp(alpha + final)
    const float v = st ? (alpha_s[tid] + fin) : -INFINITY;
    float* red = (float*)pk;
    red[tid] = v;
    __syncthreads();
    for (int off = 512; off > 0; off >>= 1) {
        if (tid < off) red[tid] = fmaxf(red[tid], red[tid + off]);
        __syncthreads();
    }
    const float M = red[0];
    __syncthreads();
    red[tid] = __expf(v - M);
    __syncthreads();
    for (int off = 512; off > 0; off >>= 1) {
        if (tid < off) red[tid] += red[tid + off];
        __syncthreads();
    }
    if (tid == 0) *res = M + __logf(red[0]);
}

// ---------------------------------------------------------------------------
// persistent cooperative kernel: phase 0 = all 256 blocks produce tile 0 W';
// then 0..15 den, 16..47 num (nt tiles, nt-1 syncs), 48..255 produce tiles
// 1..nt-1 (nt-1 syncs). One final sync, block 0 computes the loss.
// Sync count is uniform: 1 + (nt-1) + 1 for every block.
// ---------------------------------------------------------------------------
__global__ __launch_bounds__(1024) void persist_kernel(
    const int* __restrict__ seqlen,
    float* __restrict__ Wd0, float* __restrict__ Wn0,
    float* __restrict__ Wd1, float* __restrict__ Wn1,
    const unsigned* __restrict__ den_meta,
    const int* __restrict__ den_pbeg, const int* __restrict__ den_padj,
    const float* __restrict__ den_init, const float* __restrict__ den_final,
    const unsigned* __restrict__ num_meta,
    const int* __restrict__ num_pbeg, const int* __restrict__ num_padj,
    const float* __restrict__ num_init, const float* __restrict__ num_final,
    float* __restrict__ res, int nt, int Tt,
    const float* __restrict__ est,
    const unsigned* __restrict__ pxi_den, const float* __restrict__ wcsr_den,
    const unsigned* __restrict__ pxi_num, const float* __restrict__ wcsr_num,
    float* __restrict__ out)
{
    __shared__ float alpha[2048];   // dual-copy alpha (den: 2*1024)
    __shared__ float2 pk[2048];     // partials; reused as reduce buffer
    __shared__ float row_s[CC];     // wprep staging
    cg::grid_group grid = cg::this_grid();
    const int bid = blockIdx.x;
    const int tid = threadIdx.x;

    // phase 0: all blocks produce tile 0's W'
    wprep_part(bid, NWG, 0, Tt, est, pxi_den, wcsr_den, pxi_num, wcsr_num,
               Wd0, Wn0, row_s);
    __threadfence();
    grid.sync();

    if (bid < 16) {
        const int s = bid >> 3, b = bid & 7;
        const int L = seqlen[b * SS + s];
        fsm_forward_persist<16>(grid, ND, L, nt, Tt,
                                Wd0 + (size_t)bid * Tt * AD,
                                Wd1 + (size_t)bid * Tt * AD, AD,
                                den_meta, den_pbeg, den_padj,
                                den_init, den_final, &res[bid], alpha, pk);
    } else if (bid < 48) {
        const int q = bid - 16;
        const int p = q >> 4, g = q & 15;
        const int s = g >> 3, b = g & 7;
        const int sp = p ? (1 - s) : s;
        const int L = seqlen[b * SS + sp];
        fsm_forward_persist<2>(grid, NN, L, nt, Tt,
                               Wn0 + (size_t)q * Tt * AN,
                               Wn1 + (size_t)q * Tt * AN, AN,
                               num_meta + (size_t)g * AN,
                               num_pbeg + (size_t)g * (NN + 1),
                               num_padj + (size_t)g * NN,
                               num_init + (size_t)g * NN, num_final + (size_t)g * NN,
                               &res[16 + q], alpha, pk);
    } else {
        for (int k = 0; k + 1 < nt; ++k) {
            float* WdN = ((k + 1) & 1) ? Wd1 : Wd0;
            float* WnN = ((k + 1) & 1) ? Wn1 : Wn0;
            wprep_part(bid - 48, NWG - 48, (k + 1) * Tt, Tt, est,
                       pxi_den, wcsr_den, pxi_num, wcsr_num, WdN, WnN, row_s);
            __threadfence();
            grid.sync();
        }
    }
    __threadfence();
    grid.sync();
    if (bid == 0 && tid == 0) {
        float loss = 0.f;
        for (int b = 0; b < BB; ++b) {
            const float den = res[b] + res[8 + b];
            const float n0  = res[16 + b] + res[16 + 8 + b];
            const float n1  = res[32 + b] + res[32 + 8 + b];
            loss += -(fminf(n0, n1) - den);
        }
        out[0] = loss;
    }
}

// ---------------------------------------------------------------------------
// fallback launch-per-tile fused kernel (r10-verified path)
// ---------------------------------------------------------------------------
__global__ __launch_bounds__(1024) void fused_kernel(
    const int* __restrict__ seqlen,
    const float* __restrict__ Wd, const float* __restrict__ Wn,
    const unsigned* __restrict__ den_meta,
    const int* __restrict__ den_pbeg, const int* __restrict__ den_padj,
    const float* __restrict__ den_init, const float* __restrict__ den_final,
    const unsigned* __restrict__ num_meta,
    const int* __restrict__ num_pbeg, const int* __restrict__ num_padj,
    const float* __restrict__ num_init, const float* __restrict__ num_final,
    float* __restrict__ alpha_g, float* __restrict__ res,
    int t0, int Tt, int last,
    const float* __restrict__ est,
    const unsigned* __restrict__ pxi_den, const float* __restrict__ wcsr_den,
    const unsigned* __restrict__ pxi_num, const float* __restrict__ wcsr_num,
    float* __restrict__ Wd_next, float* __restrict__ Wn_next)
{
    __shared__ float alpha[2048];
    __shared__ float2 pk[2048];
    __shared__ float row_s[CC];
    const int bid = blockIdx.x;
    const bool first = (t0 == 0);
    if (bid >= 48) {
        if (!last)
            wprep_part(bid - 48, NWG - 48, t0 + Tt, Tt, est,
                       pxi_den, wcsr_den, pxi_num, wcsr_num,
                       Wd_next, Wn_next, row_s);
        return;
    }
    if (bid < 16) {
        const int s = bid >> 3, b = bid & 7;
        const int L = seqlen[b * SS + s];
        fsm_forward_tile<16>(ND, L, t0, Tt, first, last != 0,
                             Wd + (size_t)bid * Tt * AD, AD,
                             den_meta, den_pbeg, den_padj,
                             den_init, den_final,
                             alpha_g + (size_t)bid * 1024, &res[bid], alpha, pk);
    } else {
        const int q = bid - 16;
        const int p = q >> 4, g = q & 15;
        const int s = g >> 3, b = g & 7;
        const int sp = p ? (1 - s) : s;
        const int L = seqlen[b * SS + sp];
        fsm_forward_tile<2>(NN, L, t0, Tt, first, last != 0,
                            Wn + (size_t)q * Tt * AN, AN,
                            num_meta + (size_t)g * AN,
                            num_pbeg + (size_t)g * (NN + 1), num_padj + (size_t)g * NN,
                            num_init + (size_t)g * NN, num_final + (size_t)g * NN,
                            alpha_g + (size_t)bid * 1024, &res[16 + q], alpha, pk);
    }
}

__global__ void finalize_kernel(const float* __restrict__ res, float* __restrict__ out)
{
    if (threadIdx.x == 0 && blockIdx.x == 0) {
        float loss = 0.f;
        for (int b = 0; b < BB; ++b) {
            const float den = res[b] + res[8 + b];
            const float n0  = res[16 + b] + res[16 + 8 + b];
            const float n1  = res[32 + b] + res[32 + 8 + b];
            const float nm  = fminf(n0, n1);
            loss += -(nm - den);
        }
        out[0] = loss;
    }
}

extern "C" void kernel_launch(void* const* d_in, const int* in_sizes, int n_in,
                              void* d_out, int out_size, void* d_ws, size_t ws_size,
                              hipStream_t stream)
{
    const float* est       = (const float*)d_in[0];
    const int*   seqlen    = (const int*)  d_in[1];
    const int*   den_src   = (const int*)  d_in[2];
    const int*   den_dst   = (const int*)  d_in[3];
    const int*   den_pdf   = (const int*)  d_in[4];
    const float* den_w     = (const float*)d_in[5];
    const float* den_init  = (const float*)d_in[6];
    const float* den_final = (const float*)d_in[7];
    const int*   num_src   = (const int*)  d_in[8];
    const int*   num_dst   = (const int*)  d_in[9];
    const int*   num_pdf   = (const int*)  d_in[10];
    const float* num_w     = (const float*)d_in[11];
    const float* num_init  = (const float*)d_in[12];
    const float* num_final = (const float*)d_in[13];

    char* ws = (char*)d_ws;
    unsigned* den_meta = (unsigned*)(ws + 0);        //  65536 -> 65536
    unsigned* den_pxi  = (unsigned*)(ws + 65536);    //  65536 -> 131072
    float*    den_wcsr = (float*)   (ws + 131072);   //  65536 -> 196608
    unsigned* num_meta = (unsigned*)(ws + 196608);   // 131072 -> 327680
    unsigned* num_pxi  = (unsigned*)(ws + 327680);   // 131072 -> 458752
    float*    num_wcsr = (float*)   (ws + 458752);   // 131072 -> 589824
    int*      num_pbeg = (int*)     (ws + 589824);   //  16448 -> 606272
    int*      num_padj = (int*)     (ws + 606272);   //  16384 -> 622656
    int*      den_pbeg = (int*)     (ws + 622656);   //   4100 -> 626756 (pad 626816)
    int*      den_padj = (int*)     (ws + 626816);   //   4096 -> 630912
    float*    alpha_g  = (float*)   (ws + 630912);   // 196608 -> 827520
    float*    res      = (float*)   (ws + 827520);   //    192 -> 827712
    const size_t fixed = 827904;

    // den: CH=16 (LC=4); num: CH=2 (LC=1)
    prep_kernel<<<1, 1024, 0, stream>>>(den_src, den_dst, den_pdf, den_w,
                                        den_meta, den_pxi, den_wcsr,
                                        den_pbeg, den_padj, ND, AD, 4);
    prep_kernel<<<16, 256, 0, stream>>>(num_src, num_dst, num_pdf, num_w,
                                        num_meta, num_pxi, num_wcsr,
                                        num_pbeg, num_padj, NN, AN, 1);

    // W' double buffer: per buffer Tt*(16*AD + 32*AN)*4 = Tt*1310720 bytes
    int Tt = 64;
    while (Tt > 4 && fixed + 2ull * (size_t)Tt * 1310720ull > ws_size) Tt >>= 1;
    const int nt = TT / Tt;
    const size_t wbuf_f = (size_t)Tt * (16 * AD + 32 * AN);
    float* Wd0 = (float*)(ws + fixed);
    float* Wn0 = Wd0 + (size_t)16 * Tt * AD;
    float* Wd1 = Wd0 + wbuf_f;
    float* Wn1 = Wd1 + (size_t)16 * Tt * AD;
    float* outp = (float*)d_out;

    // try persistent cooperative path (one kernel, grid syncs between tiles)
    int nt_v = nt, Tt_v = Tt;
    void* kargs[] = {
        (void*)&seqlen, (void*)&Wd0, (void*)&Wn0, (void*)&Wd1, (void*)&Wn1,
        (void*)&den_meta, (void*)&den_pbeg, (void*)&den_padj,
        (void*)&den_init, (void*)&den_final,
        (void*)&num_meta, (void*)&num_pbeg, (void*)&num_padj,
        (void*)&num_init, (void*)&num_final,
        (void*)&res, (void*)&nt_v, (void*)&Tt_v,
        (void*)&est, (void*)&den_pxi, (void*)&den_wcsr,
        (void*)&num_pxi, (void*)&num_wcsr, (void*)&outp
    };
    hipError_t rc = hipLaunchCooperativeKernel(
        reinterpret_cast<const void*>(&persist_kernel),
        dim3(NWG), dim3(1024), kargs, 0, stream);

    if (rc != hipSuccess) {
        // fallback: r10-verified launch-per-tile sequence
        wprep0_kernel<<<256, 1024, 0, stream>>>(est, den_pxi, den_wcsr,
                                                num_pxi, num_wcsr, Wd0, Wn0, 0, Tt);
        for (int k = 0; k < nt; ++k) {
            float* WdC = (k & 1) ? Wd1 : Wd0;
            float* WnC = (k & 1) ? Wn1 : Wn0;
            float* WdN = (k & 1) ? Wd0 : Wd1;
            float* WnN = (k & 1) ? Wn0 : Wn1;
            fused_kernel<<<NWG, 1024, 0, stream>>>(seqlen, WdC, WnC,
                                                   den_meta, den_pbeg, den_padj,
                                                   den_init, den_final,
                                                   num_meta, num_pbeg, num_padj,
                                                   num_init, num_final,
                                                   alpha_g, res, k * Tt, Tt,
                                                   (k == nt - 1) ? 1 : 0,
                                                   est, den_pxi, den_wcsr,
                                                   num_pxi, num_wcsr, WdN, WnN);
        }
        finalize_kernel<<<1, 64, 0, stream>>>(res, outp);
    }
}

// Round 13
// 1274.279 us; speedup vs baseline: 1.8067x; 1.8067x over previous
//
#include <hip/hip_runtime.h>
#include <cstdint>
#include <cstddef>

#define BB 8
#define SS 2
#define TT 512
#define CC 2048
#define ND 1024
#define AD 16384
#define NN 256
#define AN 2048
#define NEGV -1e30f
#define NTH 1024   // fwd block threads == number of arc chunks per graph
#define NWG 256    // fused grid: 16 den + 32 num + 208 wprep workers

// ---------------------------------------------------------------------------
// prep: counting sort of arcs by dst (CSR order) into chunk-transposed SoA
//   meta = gidx | dst<<16   (gidx = LDS gather index into dual-copy alpha)
//   pxi[p] = pdf, wcsr[p] = weight (CSR order, for the W' precompute)
// plus partial-slot tables for the segmented merge:
//   pbeg = excl-scan(npart); padj[j] = pbeg[j] - (rowptr[j] >> LC)
// After the scatter, a two-choice greedy pass assigns each arc to alpha copy0
// (index src, bank src&31) or copy1 (index N + (src ^ ((src>>5)&31))), picking
// per hardware gather group (wave w, slot i == 64 lanes) the copy whose bank
// has the lower load -> near-conflict-free gathers. Value read is identical.
// One block per graph, blockDim.x == N.
// ---------------------------------------------------------------------------
__global__ void prep_kernel(const int* __restrict__ src, const int* __restrict__ dst,
                            const int* __restrict__ pdf, const float* __restrict__ w,
                            unsigned* __restrict__ meta_t, unsigned* __restrict__ pxi,
                            float* __restrict__ wcsr,
                            int* __restrict__ pbeg, int* __restrict__ padj,
                            int N, int A, int LC)
{
    __shared__ int cnt[1024];
    __shared__ int pos[1024];
    __shared__ unsigned char gcnt[8192];
    const int g = blockIdx.x;
    src += (size_t)g * A; dst += (size_t)g * A; pdf += (size_t)g * A; w += (size_t)g * A;
    meta_t += (size_t)g * A; pxi += (size_t)g * A; wcsr += (size_t)g * A;
    pbeg += (size_t)g * (N + 1); padj += (size_t)g * N;
    const int tid = threadIdx.x;
    cnt[tid] = 0;
    __syncthreads();
    for (int a = tid; a < A; a += blockDim.x) atomicAdd(&cnt[dst[a]], 1);
    __syncthreads();
    const int deg = cnt[tid];
    pos[tid] = deg;
    __syncthreads();
    for (int off = 1; off < blockDim.x; off <<= 1) {
        int add = (tid >= off) ? pos[tid - off] : 0;
        __syncthreads();
        pos[tid] += add;
        __syncthreads();
    }
    const int r0 = pos[tid] - deg;
    const int np = deg ? (((r0 + deg - 1) >> LC) - (r0 >> LC) + 1) : 0;
    __syncthreads();
    pos[tid] = np;
    __syncthreads();
    for (int off = 1; off < blockDim.x; off <<= 1) {
        int add = (tid >= off) ? pos[tid - off] : 0;
        __syncthreads();
        pos[tid] += add;
        __syncthreads();
    }
    const int pexcl = pos[tid] - np;
    pbeg[tid] = pexcl;
    if (tid == blockDim.x - 1) pbeg[N] = pexcl + np;
    padj[tid] = pexcl - (r0 >> LC);
    cnt[tid] = r0;
    __syncthreads();
    for (int a = tid; a < A; a += blockDim.x) {
        const int d2 = dst[a];
        const int p = atomicAdd(&cnt[d2], 1);
        const int l = p >> LC;
        const int i = p & ((1 << LC) - 1);
        meta_t[(size_t)i * NTH + l] = (unsigned)src[a] | ((unsigned)d2 << 16);
        pxi[p] = (unsigned)pdf[a];
        wcsr[p] = w[a];
    }
    __syncthreads();
    const int CH = 1 << LC;
    const int ngrp = (NTH / 64) * CH;
    if (tid < ngrp) {
        unsigned char* cb = &gcnt[tid * 32];
        for (int b = 0; b < 32; ++b) cb[b] = 0;
        const int i = tid & (CH - 1);
        const int w2 = tid >> LC;
        for (int lane = 0; lane < 64; ++lane) {
            const size_t idx = (size_t)i * NTH + (w2 * 64 + lane);
            const unsigned mt = meta_t[idx];
            const unsigned sv = mt & 0xffffu;
            const unsigned alt = sv ^ ((sv >> 5) & 31u);
            const int b0 = (int)(sv & 31u), b1 = (int)(alt & 31u);
            unsigned gx;
            if (cb[b1] < cb[b0]) { cb[b1]++; gx = (unsigned)N + alt; }
            else                 { cb[b0]++; gx = sv; }
            meta_t[idx] = (mt & 0xffff0000u) | gx;
        }
    }
}

// ---------------------------------------------------------------------------
// W' production for one time tile: W'[inst][trel][pos] = llh[t][pdf] + w
// (weight folded in — verified r8-r11). Row staged in LDS; coalesced
// float4 reads/writes. Layout inst-major: W'[(inst*Tt + trel)*A].
// ---------------------------------------------------------------------------
__device__ void wprep_part(int ub, int nb, int t0, int Tt, const float* __restrict__ est,
                           const unsigned* __restrict__ pxi_den,
                           const float* __restrict__ wcsr_den,
                           const unsigned* __restrict__ pxi_num,
                           const float* __restrict__ wcsr_num,
                           float* __restrict__ Wd, float* __restrict__ Wn,
                           float* row_s)
{
    const int tid = threadIdx.x;
    const int nden = 16 * Tt;
    const int total = nden + 32 * Tt;
    for (int u = ub; u < total; u += nb) {
        __syncthreads();   // previous unit's row_s readers done
        const float* row; const unsigned* pxi; const float* wcs; float* out; int n4;
        if (u < nden) {
            const int inst = u / Tt, trel = u - inst * Tt;
            const int s = inst >> 3, b = inst & 7;
            row = est + ((size_t)(b * SS + s) * TT + (t0 + trel)) * CC;
            pxi = pxi_den; wcs = wcsr_den;
            out = Wd + ((size_t)inst * Tt + trel) * AD;
            n4 = AD >> 2;
        } else {
            const int v = u - nden;
            const int inst = v / Tt, trel = v - inst * Tt;   // inst = p*16+g
            const int gg = inst & 15, p = inst >> 4;
            const int s = gg >> 3, b = gg & 7;
            const int sp = p ? (1 - s) : s;
            row = est + ((size_t)(b * SS + sp) * TT + (t0 + trel)) * CC;
            pxi = pxi_num + (size_t)gg * AN; wcs = wcsr_num + (size_t)gg * AN;
            out = Wn + ((size_t)inst * Tt + trel) * AN;
            n4 = AN >> 2;
        }
        row_s[tid] = row[tid]; row_s[tid + 1024] = row[tid + 1024];
        __syncthreads();
        const uint4* p4 = (const uint4*)pxi;
        const float4* w4 = (const float4*)wcs;
        float4* o4 = (float4*)out;
        for (int k = tid; k < n4; k += 1024) {
            const uint4 pp = p4[k];
            const float4 ww = w4[k];
            o4[k] = make_float4(row_s[pp.x] + ww.x, row_s[pp.y] + ww.y,
                                row_s[pp.z] + ww.z, row_s[pp.w] + ww.w);
        }
    }
}

__global__ __launch_bounds__(1024) void wprep0_kernel(
    const float* __restrict__ est,
    const unsigned* __restrict__ pxi_den, const float* __restrict__ wcsr_den,
    const unsigned* __restrict__ pxi_num, const float* __restrict__ wcsr_num,
    float* __restrict__ Wd, float* __restrict__ Wn, int t0, int Tt)
{
    __shared__ float row_s[CC];
    wprep_part(blockIdx.x, gridDim.x, t0, Tt, est, pxi_den, wcsr_den,
               pxi_num, wcsr_num, Wd, Wn, row_s);
}

template<int CH>
__device__ inline void load_w_row(const float* __restrict__ p, float* dst)
{
    if constexpr (CH == 16) {
        const float4* p4 = (const float4*)p;
        const float4 a = p4[0], b = p4[1], c = p4[2], d = p4[3];
        dst[0]=a.x;  dst[1]=a.y;  dst[2]=a.z;  dst[3]=a.w;
        dst[4]=b.x;  dst[5]=b.y;  dst[6]=b.z;  dst[7]=b.w;
        dst[8]=c.x;  dst[9]=c.y;  dst[10]=c.z; dst[11]=c.w;
        dst[12]=d.x; dst[13]=d.y; dst[14]=d.z; dst[15]=d.w;
    } else {
        const float2 v = *(const float2*)p;
        dst[0] = v.x; dst[1] = v.y;
    }
}

// ---------------------------------------------------------------------------
// FSM forward over one time tile [t0, t0+Tt)  (r10-verified structure):
//   phase 1 (two-pass segmented LSE): sc[] computed independently; forward
//     running-max scan with segment reset; backward select scan gives each
//     arc its segment max; independent exps; ordered sum scan emits (m, sum)
//     partials to consecutive LDS slots.
//   phase 2: owner merges its <=4 partials (batch-loaded, clamped), writes
//     both alpha copies. Reference semantics preserved:
//       mc=max(m,NEG); s'=s*exp(m-mc); new=mc+log(max(s',1e-30))
// alpha persists in global between tiles; final tile does the LSE reduce.
// ---------------------------------------------------------------------------
template<int CH>
__device__ void fsm_forward_tile(int N, int L, int t0, int Tt, bool first, bool last,
    const float* __restrict__ Wrow0, int wstride,
    const unsigned* __restrict__ meta_g,
    const int* __restrict__ pbeg_g, const int* __restrict__ padj_g,
    const float* __restrict__ initv, const float* __restrict__ finalv,
    float* __restrict__ alpha_gl, float* __restrict__ res,
    float* alpha_s, float2* pk)
{
    const int tid = threadIdx.x;
    // arc records -> registers (coalesced: element i of thread l at i*1024+l)
    unsigned meta[CH];
#pragma unroll
    for (int i = 0; i < CH; ++i) meta[i] = meta_g[i * NTH + tid];
    unsigned segmask = 0;   // bit CH-1 always set
#pragma unroll
    for (int i = 0; i < CH; ++i) {
        const int di = (int)(meta[i] >> 16);
        const int dn = (i + 1 < CH) ? (int)(meta[i + 1] >> 16) : -1;
        if (di != dn) segmask |= (1u << i);
    }
    const int slot0 = padj_g[meta[0] >> 16] + tid;  // slots consecutive per thread
    const bool st = tid < N;
    int pb0 = 0, pb1 = 0; float fin = 0.f;
    if (st) {
        const float a0 = first ? initv[tid] : alpha_gl[tid];
        alpha_s[tid] = a0;
        alpha_s[N + (tid ^ ((tid >> 5) & 31))] = a0;   // dual copy (free write)
        pb0 = pbeg_g[tid]; pb1 = pbeg_g[tid + 1];
        fin = finalv[tid];
    }
    int tb = L - t0; if (tb > Tt) tb = Tt; if (tb < 0) tb = 0;
    float wc[CH];
    if (tb > 0) load_w_row<CH>(Wrow0 + (size_t)tid * CH, wc);
    __syncthreads();

    for (int trel = 0; trel < tb; ++trel) {
        const bool pre = (trel + 1 < tb);
        float wn[CH];
        if (pre)   // prefetch next step's W'; latency hides under phase 1+2
            load_w_row<CH>(Wrow0 + (size_t)(trel + 1) * wstride + (size_t)tid * CH, wn);
        // phase 1: batch gathers, then two-pass segmented logsumexp
        float av[CH];
#pragma unroll
        for (int i = 0; i < CH; ++i)
            av[i] = alpha_s[meta[i] & 0xffffu];
        float sc[CH];
#pragma unroll
        for (int i = 0; i < CH; ++i)
            sc[i] = av[i] + wc[i];          // wc = weight + llh (folded)
        // forward running max with reset at segment ends
        float pm[CH];
        {
            float m = -INFINITY;
#pragma unroll
            for (int i = 0; i < CH; ++i) {
                m = fmaxf(m, sc[i]);
                pm[i] = m;
                if (segmask & (1u << i)) m = -INFINITY;
            }
        }
        // backward: per-arc segment max (bit CH-1 always set)
        float sm[CH];
        sm[CH - 1] = pm[CH - 1];
#pragma unroll
        for (int i = CH - 2; i >= 0; --i)
            sm[i] = (segmask & (1u << i)) ? pm[i] : sm[i + 1];
        // independent exps + ordered segmented sum, emit partials
        {
            float ssn = 0.f;
            int sl = slot0;
#pragma unroll
            for (int i = 0; i < CH; ++i) {
                ssn += __expf(sc[i] - sm[i]);
                if (segmask & (1u << i)) {
                    pk[sl] = make_float2(sm[i], ssn); ++sl;
                    ssn = 0.f;
                }
            }
        }
        __syncthreads();                                 // partials + alpha reads done
        // phase 2: owner merges partials (slot order == arc order), batch-loaded
        if (st) {
            float v2;
            const int cnt = pb1 - pb0;
            if (cnt > 0) {
                const float2 P0 = pk[pb0];
                const float2 P1 = pk[cnt > 1 ? pb0 + 1 : pb0];
                const float2 P2 = pk[cnt > 2 ? pb0 + 2 : pb0];
                const float2 P3 = pk[cnt > 3 ? pb0 + 3 : pb0];
                float mm = P0.x, s2 = P0.y;
                if (cnt > 1) {
                    const float d = P1.x - mm; const float e = __expf(-fabsf(d));
                    if (d > 0.f) { s2 = s2 * e + P1.y; mm = P1.x; } else { s2 += P1.y * e; }
                }
                if (cnt > 2) {
                    const float d = P2.x - mm; const float e = __expf(-fabsf(d));
                    if (d > 0.f) { s2 = s2 * e + P2.y; mm = P2.x; } else { s2 += P2.y * e; }
                }
                if (cnt > 3) {
                    const float d = P3.x - mm; const float e = __expf(-fabsf(d));
                    if (d > 0.f) { s2 = s2 * e + P3.y; mm = P3.x; } else { s2 += P3.y * e; }
                }
                for (int q2 = pb0 + 4; q2 < pb1; ++q2) {  // rare
                    const float2 Pq = pk[q2];
                    const float d = Pq.x - mm; const float e = __expf(-fabsf(d));
                    if (d > 0.f) { s2 = s2 * e + Pq.y; mm = Pq.x; } else { s2 += Pq.y * e; }
                }
                const float mc  = fmaxf(mm, NEGV);
                const float scs = s2 * __expf(mm - mc);
                v2 = mc + __logf(fmaxf(scs, 1e-30f));
            } else {
                v2 = NEGV + __logf(1e-30f);              // no in-arcs (matches ref)
            }
            alpha_s[tid] = v2;
            alpha_s[N + (tid ^ ((tid >> 5) & 31))] = v2;
        }
        __syncthreads();
        if (pre) {
#pragma unroll
            for (int i = 0; i < CH; ++i) wc[i] = wn[i];
        }
    }

    if (last) {
        // logsumexp(alpha + final) over N states, block-wide tree reduce
        const float v = st ? (alpha_s[tid] + fin) : -INFINITY;
        float* red = (float*)pk;
        red[tid] = v;
        __syncthreads();
        for (int off = 512; off > 0; off >>= 1) {
            if (tid < off) red[tid] = fmaxf(red[tid], red[tid + off]);
            __syncthreads();
        }
        const float M = red[0];
        __syncthreads();
        red[tid] = __expf(v - M);
        __syncthreads();
        for (int off = 512; off > 0; off >>= 1) {
            if (tid < off) red[tid] += red[tid + off];
            __syncthreads();
        }
        if (tid == 0) *res = M + __logf(red[0]);
    } else if (st) {
        alpha_gl[tid] = alpha_s[tid];
    }
}

// ---------------------------------------------------------------------------
// fused (grid NWG=256): blocks 0..15 den fwd (tile k); 16..47 num fwd (tile
// k); 48..255 produce W' for tile k+1 across 208 CUs (hidden under den time).
// ---------------------------------------------------------------------------
__global__ __launch_bounds__(1024) void fused_kernel(
    const int* __restrict__ seqlen,
    const float* __restrict__ Wd, const float* __restrict__ Wn,
    const unsigned* __restrict__ den_meta,
    const int* __restrict__ den_pbeg, const int* __restrict__ den_padj,
    const float* __restrict__ den_init, const float* __restrict__ den_final,
    const unsigned* __restrict__ num_meta,
    const int* __restrict__ num_pbeg, const int* __restrict__ num_padj,
    const float* __restrict__ num_init, const float* __restrict__ num_final,
    float* __restrict__ alpha_g, float* __restrict__ res,
    int t0, int Tt, int last,
    const float* __restrict__ est,
    const unsigned* __restrict__ pxi_den, const float* __restrict__ wcsr_den,
    const unsigned* __restrict__ pxi_num, const float* __restrict__ wcsr_num,
    float* __restrict__ Wd_next, float* __restrict__ Wn_next)
{
    __shared__ float alpha[2048];   // dual-copy alpha (den: 2*1024)
    __shared__ float2 pk[2048];     // partials; reused as reduce buffer
    __shared__ float row_s[CC];     // wprep staging (worker blocks only)
    const int bid = blockIdx.x;
    const bool first = (t0 == 0);
    if (bid >= 48) {
        if (!last)   // produce next tile's W', spread over 208 CUs
            wprep_part(bid - 48, NWG - 48, t0 + Tt, Tt, est,
                       pxi_den, wcsr_den, pxi_num, wcsr_num,
                       Wd_next, Wn_next, row_s);
        return;
    }
    if (bid < 16) {
        const int s = bid >> 3, b = bid & 7;
        const int L = seqlen[b * SS + s];
        fsm_forward_tile<16>(ND, L, t0, Tt, first, last != 0,
                             Wd + (size_t)bid * Tt * AD, AD,
                             den_meta, den_pbeg, den_padj,
                             den_init, den_final,
                             alpha_g + (size_t)bid * 1024, &res[bid], alpha, pk);
    } else {
        const int q = bid - 16;
        const int p = q >> 4, g = q & 15;
        const int s = g >> 3, b = g & 7;
        const int sp = p ? (1 - s) : s;
        const int L = seqlen[b * SS + sp];
        fsm_forward_tile<2>(NN, L, t0, Tt, first, last != 0,
                            Wn + (size_t)q * Tt * AN, AN,
                            num_meta + (size_t)g * AN,
                            num_pbeg + (size_t)g * (NN + 1), num_padj + (size_t)g * NN,
                            num_init + (size_t)g * NN, num_final + (size_t)g * NN,
                            alpha_g + (size_t)bid * 1024, &res[16 + q], alpha, pk);
    }
}

// res layout: [0..15] den (s*8+b), [16..31] num perm0, [32..47] num perm1
__global__ void finalize_kernel(const float* __restrict__ res, float* __restrict__ out)
{
    if (threadIdx.x == 0 && blockIdx.x == 0) {
        float loss = 0.f;
        for (int b = 0; b < BB; ++b) {
            const float den = res[b] + res[8 + b];
            const float n0  = res[16 + b] + res[16 + 8 + b];
            const float n1  = res[32 + b] + res[32 + 8 + b];
            const float nm  = fminf(n0, n1);
            loss += -(nm - den);
        }
        out[0] = loss;
    }
}

extern "C" void kernel_launch(void* const* d_in, const int* in_sizes, int n_in,
                              void* d_out, int out_size, void* d_ws, size_t ws_size,
                              hipStream_t stream)
{
    const float* est       = (const float*)d_in[0];
    const int*   seqlen    = (const int*)  d_in[1];
    const int*   den_src   = (const int*)  d_in[2];
    const int*   den_dst   = (const int*)  d_in[3];
    const int*   den_pdf   = (const int*)  d_in[4];
    const float* den_w     = (const float*)d_in[5];
    const float* den_init  = (const float*)d_in[6];
    const float* den_final = (const float*)d_in[7];
    const int*   num_src   = (const int*)  d_in[8];
    const int*   num_dst   = (const int*)  d_in[9];
    const int*   num_pdf   = (const int*)  d_in[10];
    const float* num_w     = (const float*)d_in[11];
    const float* num_init  = (const float*)d_in[12];
    const float* num_final = (const float*)d_in[13];

    char* ws = (char*)d_ws;
    unsigned* den_meta = (unsigned*)(ws + 0);        //  65536 -> 65536
    unsigned* den_pxi  = (unsigned*)(ws + 65536);    //  65536 -> 131072
    float*    den_wcsr = (float*)   (ws + 131072);   //  65536 -> 196608
    unsigned* num_meta = (unsigned*)(ws + 196608);   // 131072 -> 327680
    unsigned* num_pxi  = (unsigned*)(ws + 327680);   // 131072 -> 458752
    float*    num_wcsr = (float*)   (ws + 458752);   // 131072 -> 589824
    int*      num_pbeg = (int*)     (ws + 589824);   //  16448 -> 606272
    int*      num_padj = (int*)     (ws + 606272);   //  16384 -> 622656
    int*      den_pbeg = (int*)     (ws + 622656);   //   4100 -> 626756 (pad 626816)
    int*      den_padj = (int*)     (ws + 626816);   //   4096 -> 630912
    float*    alpha_g  = (float*)   (ws + 630912);   // 196608 -> 827520
    float*    res      = (float*)   (ws + 827520);   //    192 -> 827712
    const size_t fixed = 827904;

    // W' double buffer: per buffer Tt*(16*AD + 32*AN)*4 = Tt*1310720 bytes
    int Tt = 64;
    while (Tt > 4 && fixed + 2ull * (size_t)Tt * 1310720ull > ws_size) Tt >>= 1;
    const size_t wbuf_f = (size_t)Tt * (16 * AD + 32 * AN);
    float* Wd0 = (float*)(ws + fixed);
    float* Wn0 = Wd0 + (size_t)16 * Tt * AD;
    float* Wd1 = Wd0 + wbuf_f;
    float* Wn1 = Wd1 + (size_t)16 * Tt * AD;

    // den: CH=16 (LC=4); num: CH=2 (LC=1)
    prep_kernel<<<1, 1024, 0, stream>>>(den_src, den_dst, den_pdf, den_w,
                                        den_meta, den_pxi, den_wcsr,
                                        den_pbeg, den_padj, ND, AD, 4);
    prep_kernel<<<16, 256, 0, stream>>>(num_src, num_dst, num_pdf, num_w,
                                        num_meta, num_pxi, num_wcsr,
                                        num_pbeg, num_padj, NN, AN, 1);

    wprep0_kernel<<<256, 1024, 0, stream>>>(est, den_pxi, den_wcsr,
                                            num_pxi, num_wcsr, Wd0, Wn0, 0, Tt);

    const int nt = TT / Tt;
    for (int k = 0; k < nt; ++k) {
        float* WdC = (k & 1) ? Wd1 : Wd0;
        float* WnC = (k & 1) ? Wn1 : Wn0;
        float* WdN = (k & 1) ? Wd0 : Wd1;
        float* WnN = (k & 1) ? Wn0 : Wn1;
        fused_kernel<<<NWG, 1024, 0, stream>>>(seqlen, WdC, WnC,
                                               den_meta, den_pbeg, den_padj,
                                               den_init, den_final,
                                               num_meta, num_pbeg, num_padj,
                                               num_init, num_final,
                                               alpha_g, res, k * Tt, Tt,
                                               (k == nt - 1) ? 1 : 0,
                                               est, den_pxi, den_wcsr,
                                               num_pxi, num_wcsr, WdN, WnN);
    }

    finalize_kernel<<<1, 64, 0, stream>>>(res, (float*)d_out);
}